// Round 21
// baseline (506.055 us; speedup 1.0000x reference)
//
#include <hip/hip_runtime.h>
#include <math.h>

#define BB   128
#define DECD 512
#define E2D  1024
#define EMBD 256
#define S1D  200
#define S2D  200
#define SJD  400
#define VV   50000
#define NEGV (-1e10f)
#define JY   800   // joint tiles (51200 rows / 64); copy tiles follow

typedef unsigned short u16;
typedef __bf16 bf16x8 __attribute__((ext_vector_type(8)));
typedef float f32x4 __attribute__((ext_vector_type(4)));
typedef u16 u16x8 __attribute__((ext_vector_type(8)));

__device__ __forceinline__ u16 f2bf(float x) {
  unsigned u = __float_as_uint(x);
  unsigned r = (u + 0x7fffu + ((u >> 16) & 1u)) >> 16;
  return (u16)r;
}
__device__ __forceinline__ float bf2f(u16 h) {
  return __uint_as_float(((unsigned)h) << 16);
}
// hardware RTNE pack (r7/r16-r20-verified)
__device__ __forceinline__ u16x8 cvt8h(float4 a, float4 b) {
  bf16x8 r;
  r[0] = (__bf16)a.x; r[1] = (__bf16)a.y; r[2] = (__bf16)a.z; r[3] = (__bf16)a.w;
  r[4] = (__bf16)b.x; r[5] = (__bf16)b.y; r[6] = (__bf16)b.z; r[7] = (__bf16)b.w;
  return *reinterpret_cast<u16x8*>(&r);
}

typedef const __attribute__((address_space(1))) void* gas_t;
typedef __attribute__((address_space(3))) void* las_t;
__device__ __forceinline__ void async_copy16(const u16* g, u16* l) {
  __builtin_amdgcn_global_load_lds((gas_t)g, (las_t)l, 16, 0, 0);
}

// ---------------- fused prep (r16-r20-verified): wt2 | cvt hid | hWa | embx ----------------
__global__ __launch_bounds__(256) void k_prep(
    const float* __restrict__ Wa, const float* __restrict__ Wc,
    u16* __restrict__ Wta, u16* __restrict__ Wtc,
    const float* __restrict__ hidden, u16* __restrict__ hid_bf,
    const float* __restrict__ attn_b, float* __restrict__ hWa,
    const int* __restrict__ inp, const float* __restrict__ table,
    u16* __restrict__ x_bf) {
  int blk = blockIdx.x, tid = threadIdx.x;
  if (blk < 1024) {
    __shared__ float t[32][33];
    int z = blk >> 9, rem = blk & 511;
    int bk = rem & 31, bn = rem >> 5;
    const float* W = z ? Wc : Wa;
    u16* Wt = z ? Wtc : Wta;
    int tx = tid & 31, ty = tid >> 5;
    #pragma unroll
    for (int r = 0; r < 4; ++r) {
      int k = bk * 32 + ty + r * 8;
      t[ty + r * 8][tx] = W[(size_t)(512 + k) * 512 + bn * 32 + tx];
    }
    __syncthreads();
    #pragma unroll
    for (int r = 0; r < 4; ++r) {
      int n = bn * 32 + ty + r * 8;
      Wt[(size_t)n * 1024 + bk * 32 + tx] = f2bf(t[tx][ty + r * 8]);
    }
  } else if (blk < 1056) {
    int i = (blk - 1024) * 256 + tid;
    const float4 f0 = *(const float4*)(hidden + (size_t)i * 8);
    const float4 f1 = *(const float4*)(hidden + (size_t)i * 8 + 4);
    *(u16x8*)(hid_bf + (size_t)i * 8) = cvt8h(f0, f1);
  } else if (blk < 1312) {
    int idx = blk - 1056;
    int b = idx >> 1;
    int d = (idx & 1) * 256 + tid;
    const float* hr = hidden + (size_t)b * DECD;
    float acc = attn_b[d];
    #pragma unroll 8
    for (int k = 0; k < DECD; ++k) acc += hr[k] * Wa[(size_t)k * DECD + d];
    hWa[(size_t)b * DECD + d] = acc;
  } else {
    int b = blk - 1312;
    x_bf[(size_t)b * 1280 + tid] = f2bf(table[(size_t)inp[b] * EMBD + tid]);
  }
}

// ---------------- combined joint+copy energy GEMM (r19-verified raceless structure; preC bf16) ----------------
__global__ __launch_bounds__(256) void gemm_energy_jc(
    const float* __restrict__ enc1, const float* __restrict__ enc2,
    const u16* __restrict__ BtA, const u16* __restrict__ BtC,
    const float* __restrict__ hW, const float* __restrict__ v,
    float* __restrict__ partJ, u16* __restrict__ preC) {
  __shared__ u16 As[2][64 * 32];   // 2 x 4 KB
  __shared__ u16 Bs[256 * 32];     // 16 KB
  __shared__ float sbuf[64][2];
  int tid = threadIdx.x;
  int wid = tid >> 6, lane = tid & 63;
  int wr = wid >> 1, wc = wid & 1;
  int bn = blockIdx.x;
  int jy = blockIdx.y;
  int joint = (jy < JY);
  size_t m0 = joint ? (size_t)jy * 64 : (size_t)(jy - JY) * 64;
  int bhalf = (jy & 1) * 64;
  int n0 = bn * 256;

  int rA = tid >> 2, cslot = tid & 3;
  int lAoff = rA * 32 + ((cslot ^ ((rA >> 1) & 3)) * 8);
  const float* base;
  if (joint)
    base = (m0 < (size_t)S1D * BB) ? (enc1 + m0 * E2D)
                                   : (enc2 + (m0 - (size_t)S1D * BB) * E2D);
  else
    base = enc1 + m0 * E2D;
  const float* gA_f = base + (size_t)rA * E2D + cslot * 8;

  const u16* Bt = joint ? BtA : BtC;
  const u16* gB[4];
  #pragma unroll
  for (int i = 0; i < 4; ++i) {
    int rn = i * 64 + wid * 16 + (lane >> 2);
    int c = (lane & 3) ^ ((rn >> 1) & 3);
    gB[i] = Bt + (size_t)(n0 + rn) * E2D + c * 8;
  }

  int q = lane >> 4, cl = lane & 15;
  int aoff[2], boff[8];
  #pragma unroll
  for (int mi = 0; mi < 2; ++mi) {
    int row = wr * 32 + mi * 16 + cl;
    aoff[mi] = row * 64 + ((q ^ ((row >> 1) & 3)) * 16);
  }
  #pragma unroll
  for (int nj = 0; nj < 8; ++nj) {
    int rn = wc * 128 + nj * 16 + cl;
    boff[nj] = rn * 64 + ((q ^ ((rn >> 1) & 3)) * 16);
  }

  f32x4 acc[2][8];
  #pragma unroll
  for (int mi = 0; mi < 2; ++mi)
    #pragma unroll
    for (int nj = 0; nj < 8; ++nj) {
      f32x4 z = {0.f, 0.f, 0.f, 0.f};
      acc[mi][nj] = z;
    }

  float4 a0 = *(const float4*)(gA_f);
  float4 a1 = *(const float4*)(gA_f + 4);
  *(u16x8*)(&As[0][lAoff]) = cvt8h(a0, a1);
  a0 = *(const float4*)(gA_f + 32);
  a1 = *(const float4*)(gA_f + 36);

  for (int t = 0; t < 32; ++t) {
    int cur = t & 1, nxt = cur ^ 1;
    int k0 = t * 32, k1 = k0 + 32;
    #pragma unroll
    for (int i = 0; i < 4; ++i) async_copy16(gB[i] + k0, &Bs[2048 * i + wid * 512]);
    if (t < 31) {
      *(u16x8*)(&As[nxt][lAoff]) = cvt8h(a0, a1);
      if (t < 30) {
        a0 = *(const float4*)(gA_f + k1 + 32);
        a1 = *(const float4*)(gA_f + k1 + 36);
      }
    }
    __syncthreads();   // B (and next-A) staged & visible
    bf16x8 af[2];
    #pragma unroll
    for (int mi = 0; mi < 2; ++mi)
      af[mi] = *(const bf16x8*)((const char*)As[cur] + aoff[mi]);
    #pragma unroll
    for (int nj = 0; nj < 8; ++nj) {
      bf16x8 bg = *(const bf16x8*)((const char*)Bs + boff[nj]);
      acc[0][nj] = __builtin_amdgcn_mfma_f32_16x16x32_bf16(af[0], bg, acc[0][nj], 0, 0, 0);
      acc[1][nj] = __builtin_amdgcn_mfma_f32_16x16x32_bf16(af[1], bg, acc[1][nj], 0, 0, 0);
    }
    __syncthreads();   // readers done before next-step B overwrite
  }

  if (joint) {
    #pragma unroll
    for (int mi = 0; mi < 2; ++mi) {
      #pragma unroll
      for (int j = 0; j < 4; ++j) {
        int m = wr * 32 + mi * 16 + q * 4 + j;
        float s = 0.f;
        #pragma unroll
        for (int nj = 0; nj < 8; ++nj) {
          int d = n0 + wc * 128 + nj * 16 + cl;
          s += tanhf(acc[mi][nj][j] + hW[(size_t)(bhalf + m) * DECD + d]) * v[d];
        }
        s += __shfl_xor(s, 1, 64);
        s += __shfl_xor(s, 2, 64);
        s += __shfl_xor(s, 4, 64);
        s += __shfl_xor(s, 8, 64);
        if (cl == 0) sbuf[m][wc] = s;
      }
    }
    __syncthreads();
    if (tid < 64)
      partJ[(size_t)bn * 51200 + m0 + tid] = sbuf[tid][0] + sbuf[tid][1];
  } else {
    #pragma unroll
    for (int mi = 0; mi < 2; ++mi) {
      #pragma unroll
      for (int nj = 0; nj < 8; ++nj) {
        int d = n0 + wc * 128 + nj * 16 + cl;
        #pragma unroll
        for (int j = 0; j < 4; ++j) {
          int m = wr * 32 + mi * 16 + q * 4 + j;
          preC[(m0 + m) * (size_t)DECD + d] = f2bf(acc[mi][nj][j]);
        }
      }
    }
  }
}

// weighted partials with inline joint softmax (r16-r20-verified; unroll 8)
__global__ __launch_bounds__(256) void k_wpart_sm(const float* __restrict__ part,
    const float* __restrict__ enc1, const float* __restrict__ enc2,
    const int* __restrict__ m1, const int* __restrict__ m2,
    float* __restrict__ wp) {
  int b = blockIdx.x, tid = threadIdx.x;
  int e2 = blockIdx.y * 256 + tid;
  int scn = blockIdx.z;
  __shared__ float sm[4];
  __shared__ float ws[100];
  int s0 = tid, s2 = tid + 256;
  float a0, a1 = -INFINITY;
  {
    int msk = (s0 < S1D) ? m1[b * S1D + s0] : m2[b * S2D + (s0 - S1D)];
    int m = s0 * 128 + b;
    a0 = msk ? (part[m] + part[51200 + m]) : NEGV;
  }
  if (s2 < SJD) {
    int msk = (s2 < S1D) ? m1[b * S1D + s2] : m2[b * S2D + (s2 - S1D)];
    int m = s2 * 128 + b;
    a1 = msk ? (part[m] + part[51200 + m]) : NEGV;
  }
  float vmax = fmaxf(a0, a1);
  #pragma unroll
  for (int off = 32; off > 0; off >>= 1) vmax = fmaxf(vmax, __shfl_down(vmax, off, 64));
  int lane = tid & 63, wid = tid >> 6;
  if (lane == 0) sm[wid] = vmax;
  __syncthreads();
  vmax = fmaxf(fmaxf(sm[0], sm[1]), fmaxf(sm[2], sm[3]));
  __syncthreads();
  float lsum = expf(a0 - vmax);
  if (s2 < SJD) lsum += expf(a1 - vmax);
  #pragma unroll
  for (int off = 32; off > 0; off >>= 1) lsum += __shfl_down(lsum, off, 64);
  if (lane == 0) sm[wid] = lsum;
  __syncthreads();
  float inv = 1.0f / (sm[0] + sm[1] + sm[2] + sm[3]);
  if (tid < 100) {
    int s = scn * 100 + tid;
    int msk = (s < S1D) ? m1[b * S1D + s] : m2[b * S2D + (s - S1D)];
    int m = s * 128 + b;
    float av = msk ? (part[m] + part[51200 + m]) : NEGV;
    ws[tid] = expf(av - vmax) * inv;
  }
  __syncthreads();
  float acc0 = 0.f, acc1 = 0.f;
  #pragma unroll 8
  for (int i = 0; i < 100; ++i) {
    int s = scn * 100 + i;
    const float* ep = (s < S1D) ? (enc1 + ((size_t)s * BB + b) * E2D)
                                : (enc2 + ((size_t)(s - S1D) * BB + b) * E2D);
    float2 u = *(const float2*)(ep + e2 * 2);
    float w = ws[i];
    acc0 += w * u.x;
    acc1 += w * u.y;
  }
  float* dst = wp + ((size_t)scn * BB + b) * E2D + e2 * 2;
  dst[0] = acc0;
  dst[1] = acc1;
}

__global__ __launch_bounds__(256) void k_wsum_x(const float* __restrict__ wp,
    float* __restrict__ wgt, u16* __restrict__ x) {
  int i = blockIdx.x * 256 + threadIdx.x;
  const int NN = BB * E2D;
  float s = wp[i] + wp[NN + i] + wp[2 * NN + i] + wp[3 * NN + i];
  wgt[i] = s;
  int b = i >> 10, e = i & 1023;
  x[(size_t)b * 1280 + EMBD + e] = f2bf(s);
}

// ---------------- fc3-style body (BN=64, 512 thr) as device function (r18-r20-verified) ----------------
__device__ __forceinline__ void fc3_body(
    const u16* __restrict__ A, const float* __restrict__ Bf,
    const float* __restrict__ bias, float* __restrict__ C,
    int N, int K, int n0, u16* smem) {
  u16* As0 = smem;            u16* As1 = smem + 4096;
  u16* Bs0 = smem + 8192;     u16* Bs1 = smem + 10240;
  u16* AsH[2] = {As0, As1};
  u16* BsH[2] = {Bs0, Bs1};
  int tid = threadIdx.x;
  int wid = tid >> 6, lane = tid & 63;
  int wr = wid >> 2, wc = wid & 3;

  int rowa = wid * 16 + (lane >> 2);
  int ca = (lane & 3) ^ ((rowa >> 1) & 3);
  const u16* gA = A + (size_t)rowa * K + ca * 8;

  int rB = tid >> 3, cB = tid & 7;
  int gnB = n0 + rB; if (gnB >= N) gnB = N - 1;
  const float* gB = Bf + (size_t)gnB * K + cB * 8;
  int hB = cB >> 2, s4 = cB & 3;
  int lBoff = rB * 32 + ((s4 ^ ((rB >> 1) & 3)) * 8);

  int q = lane >> 4, cl = lane & 15;
  int aoff[4], boff;
  #pragma unroll
  for (int mi = 0; mi < 4; ++mi) {
    int row = wr * 64 + mi * 16 + cl;
    aoff[mi] = row * 64 + ((q ^ ((row >> 1) & 3)) * 16);
  }
  {
    int rn = wc * 16 + cl;
    boff = rn * 64 + ((q ^ ((rn >> 1) & 3)) * 16);
  }

  f32x4 acc[4];
  #pragma unroll
  for (int mi = 0; mi < 4; ++mi) {
    f32x4 z = {0.f, 0.f, 0.f, 0.f};
    acc[mi] = z;
  }

  float4 b0 = *(const float4*)(gB);
  float4 b1 = *(const float4*)(gB + 4);

  for (int k0 = 0; k0 < K; k0 += 64) {
    *(u16x8*)(&BsH[hB][lBoff]) = cvt8h(b0, b1);
    async_copy16(gA + k0,      &As0[wid * 512]);
    async_copy16(gA + k0 + 32, &As1[wid * 512]);
    __syncthreads();
    if (k0 + 64 < K) {
      b0 = *(const float4*)(gB + k0 + 64);
      b1 = *(const float4*)(gB + k0 + 68);
    }
    #pragma unroll
    for (int h = 0; h < 2; ++h) {
      bf16x8 af[4];
      #pragma unroll
      for (int mi = 0; mi < 4; ++mi) af[mi] = *(const bf16x8*)((const char*)AsH[h] + aoff[mi]);
      bf16x8 bg = *(const bf16x8*)((const char*)BsH[h] + boff);
      #pragma unroll
      for (int mi = 0; mi < 4; ++mi)
        acc[mi] = __builtin_amdgcn_mfma_f32_16x16x32_bf16(af[mi], bg, acc[mi], 0, 0, 0);
    }
    __syncthreads();
  }

  int n = n0 + wc * 16 + cl;
  if (n < N) {
    float bv = bias[n];
    #pragma unroll
    for (int mi = 0; mi < 4; ++mi)
      #pragma unroll
      for (int j = 0; j < 4; ++j) {
        int m = wr * 64 + mi * 16 + q * 4 + j;
        C[(size_t)m * N + n] = acc[mi][j] + bv;
      }
  }
}

// merged GRU GEMMs, BN=64 x 48 blocks (r19/r20-verified)
__global__ __launch_bounds__(512) void gemm_gru2(
    const u16* __restrict__ x_bf, const float* __restrict__ Wih,
    const float* __restrict__ bih, float* __restrict__ gx,
    const u16* __restrict__ h_bf, const float* __restrict__ Whh,
    const float* __restrict__ bhh, float* __restrict__ gh) {
  __shared__ u16 smem[12288];
  if (blockIdx.x < 24)
    fc3_body(x_bf, Wih, bih, gx, 1536, 1280, blockIdx.x * 64, smem);
  else
    fc3_body(h_bf, Whh, bhh, gh, 1536, 512, (blockIdx.x - 24) * 64, smem);
}

// ---------------- combined fc3 + pgen + copy-epilogue (r18-r20-verified; preC bf16) ----------------
__global__ __launch_bounds__(512) void gemm_fc3c(
    const u16* __restrict__ A, const float* __restrict__ Bf,
    const float* __restrict__ bias, float* __restrict__ C, int N, int K,
    const float* __restrict__ wgt, const int* __restrict__ inp,
    const float* __restrict__ table, const float* __restrict__ gW,
    const float* __restrict__ gb, float* __restrict__ pg,
    const float* __restrict__ hnew, const float* __restrict__ copy_W,
    const float* __restrict__ copy_b, const float* __restrict__ copy_v,
    const u16* __restrict__ preC, float* __restrict__ scC) {
  __shared__ u16 smem[12288];   // 24.6 KB pool, aliased per role
  int tid = threadIdx.x;
  if (blockIdx.x >= 256) {
    fc3_body(A, Bf, bias, C, N, K, (blockIdx.x - 256) * 64, smem);
  } else if (blockIdx.x < 128) {
    // ---- p_gen per b (r16-r20-verified math) ----
    int b = blockIdx.x;
    float* sm = (float*)smem;
    float s = 0.f;
    for (int k = tid; k < E2D + EMBD; k += 512)
      s += gW[k] * ((k < E2D) ? wgt[(size_t)b * E2D + k]
                              : table[(size_t)inp[b] * EMBD + k - E2D]);
    #pragma unroll
    for (int off = 32; off > 0; off >>= 1) s += __shfl_down(s, off, 64);
    int lane = tid & 63, wid = tid >> 6;
    if (lane == 0) sm[wid] = s;
    __syncthreads();
    if (tid == 0) {
      float t = sm[0] + sm[1] + sm[2] + sm[3] + sm[4] + sm[5] + sm[6] + sm[7] + gb[0];
      pg[b] = 1.f / (1.f + expf(-t));
    }
  } else {
    // ---- copy epilogue per b (r17-r20-verified; bf16 preC reads) ----
    int b = blockIdx.x - 128;
    float* hn  = (float*)smem;          // 512 floats
    float* hwc = (float*)smem + 512;    // 512 floats
    hn[tid] = hnew[(size_t)b * DECD + tid];
    __syncthreads();
    {
      float acc = copy_b[tid];
      #pragma unroll 8
      for (int k = 0; k < DECD; ++k) acc += hn[k] * copy_W[(size_t)k * DECD + tid];
      hwc[tid] = acc;
    }
    __syncthreads();
    int wid = tid >> 6, lane = tid & 63;
    float4 h0 = *(const float4*)(hwc + lane * 8);
    float4 h1 = *(const float4*)(hwc + lane * 8 + 4);
    float4 v0 = *(const float4*)(copy_v + lane * 8);
    float4 v1 = *(const float4*)(copy_v + lane * 8 + 4);
    for (int s = wid; s < S1D; s += 8) {
      const u16* pr = preC + ((size_t)s * 128 + b) * DECD + lane * 8;
      u16x8 pv = *(const u16x8*)(pr);
      float e = tanhf(bf2f(pv[0]) + h0.x) * v0.x + tanhf(bf2f(pv[1]) + h0.y) * v0.y
              + tanhf(bf2f(pv[2]) + h0.z) * v0.z + tanhf(bf2f(pv[3]) + h0.w) * v0.w
              + tanhf(bf2f(pv[4]) + h1.x) * v1.x + tanhf(bf2f(pv[5]) + h1.y) * v1.y
              + tanhf(bf2f(pv[6]) + h1.z) * v1.z + tanhf(bf2f(pv[7]) + h1.w) * v1.w;
      #pragma unroll
      for (int off = 32; off > 0; off >>= 1) e += __shfl_xor(e, off, 64);
      if (lane == 0) scC[(size_t)b * S1D + s] = e;
    }
  }
}

// GRU pointwise + fused concat (r15-r20-verified)
__global__ __launch_bounds__(256) void k_gru_concat(const float* __restrict__ gx,
    const float* __restrict__ gh, const float* __restrict__ hidden,
    const float* __restrict__ wgt, float* __restrict__ hnew,
    u16* __restrict__ st) {
  int b = blockIdx.x, tid = threadIdx.x;
  #pragma unroll
  for (int qq = 0; qq < 2; ++qq) {
    int d = tid + qq * 256;
    size_t o = (size_t)b * 1536;
    float xr = gx[o + d],        hr = gh[o + d];
    float xz = gx[o + 512 + d],  hz = gh[o + 512 + d];
    float xn = gx[o + 1024 + d], hn = gh[o + 1024 + d];
    float r = 1.f / (1.f + expf(-(xr + hr)));
    float z = 1.f / (1.f + expf(-(xz + hz)));
    float n = tanhf(xn + r * hn);
    float hv = (1.f - z) * n + z * hidden[(size_t)b * DECD + d];
    hnew[(size_t)b * DECD + d] = hv;
    st[(size_t)b * 1536 + d] = f2bf(hv);
  }
  #pragma unroll
  for (int qq = 0; qq < 4; ++qq) {
    int e = tid + qq * 256;
    st[(size_t)b * 1536 + DECD + e] = f2bf(wgt[(size_t)b * E2D + e]);
  }
}

// vocab softmax (single-pass online) + p_gen scale + copy-softmax + scatter (r18-r20-verified)
__global__ __launch_bounds__(256) void k_vocab_sc2(float* __restrict__ dist,
    const float* __restrict__ pg, const float* __restrict__ scC,
    const int* __restrict__ m1, const int* __restrict__ tr,
    const int* __restrict__ src1) {
  int b = blockIdx.x, tid = threadIdx.x;
  float* row = dist + (size_t)b * VV;
  __shared__ float smM[4], smS[4];
  int lane = tid & 63, wid = tid >> 6;
  float m = -INFINITY, s = 0.f;
  for (int i = tid; i < VV; i += 256) {
    float x = row[i];
    float mn = fmaxf(m, x);
    s = s * expf(m - mn) + expf(x - mn);
    m = mn;
  }
  #pragma unroll
  for (int off = 32; off > 0; off >>= 1) {
    float mo = __shfl_down(m, off, 64);
    float so = __shfl_down(s, off, 64);
    float mn = fmaxf(m, mo);
    s = s * expf(m - mn) + so * expf(mo - mn);
    m = mn;
  }
  if (lane == 0) { smM[wid] = m; smS[wid] = s; }
  __syncthreads();
  if (tid == 0) {
    float mt = smM[0], st = smS[0];
    #pragma unroll
    for (int i = 1; i < 4; ++i) {
      float mn = fmaxf(mt, smM[i]);
      st = st * expf(mt - mn) + smS[i] * expf(smM[i] - mn);
      mt = mn;
    }
    smM[0] = mt; smS[0] = st;
  }
  __syncthreads();
  m = smM[0];
  s = smS[0];
  float pgb = pg[b];
  float scale = pgb / s;
  for (int i = tid; i < VV; i += 256) row[i] = expf(row[i] - m) * scale;
  __syncthreads();
  float c0 = -INFINITY;
  if (tid < S1D) {
    int msk = m1[b * S1D + tid] * tr[b * S1D + tid];
    c0 = msk ? scC[(size_t)b * S1D + tid] : NEGV;
  }
  float cmax = c0;
  #pragma unroll
  for (int off = 32; off > 0; off >>= 1) cmax = fmaxf(cmax, __shfl_down(cmax, off, 64));
  if (lane == 0) smM[wid] = cmax;
  __syncthreads();
  cmax = fmaxf(fmaxf(smM[0], smM[1]), fmaxf(smM[2], smM[3]));
  __syncthreads();
  float csum = (tid < S1D) ? expf(c0 - cmax) : 0.f;
  #pragma unroll
  for (int off = 32; off > 0; off >>= 1) csum += __shfl_down(csum, off, 64);
  if (lane == 0) smS[wid] = csum;
  __syncthreads();
  float cinv = 1.0f / (smS[0] + smS[1] + smS[2] + smS[3]);
  if (tid < S1D) {
    float val = (1.f - pgb) * expf(c0 - cmax) * cinv;
    int tok = src1[(size_t)tid * BB + b];
    atomicAdd(&row[tok], val);
  }
}

extern "C" void kernel_launch(void* const* d_in, const int* in_sizes, int n_in,
                              void* d_out, int out_size, void* d_ws, size_t ws_size,
                              hipStream_t stream) {
  (void)in_sizes; (void)n_in; (void)out_size; (void)ws_size;
  const int*   input  = (const int*)d_in[0];
  const float* hidden = (const float*)d_in[1];
  const int*   src1   = (const int*)d_in[2];
  const float* enc1   = (const float*)d_in[3];
  const int*   mask1  = (const int*)d_in[4];
  const int*   triple = (const int*)d_in[5];
  const float* enc2   = (const float*)d_in[6];
  const int*   mask2  = (const int*)d_in[7];
  const float* embedding = (const float*)d_in[8];
  const float* attn_W = (const float*)d_in[9];
  const float* attn_b = (const float*)d_in[10];
  const float* attn_v = (const float*)d_in[11];
  const float* copy_W = (const float*)d_in[12];
  const float* copy_b = (const float*)d_in[13];
  const float* copy_v = (const float*)d_in[14];
  const float* gru_Wih = (const float*)d_in[15];
  const float* gru_Whh = (const float*)d_in[16];
  const float* gru_bih = (const float*)d_in[17];
  const float* gru_bhh = (const float*)d_in[18];
  const float* fc_W   = (const float*)d_in[19];
  const float* fc_b   = (const float*)d_in[20];
  const float* gate_W = (const float*)d_in[21];
  const float* gate_b = (const float*)d_in[22];

  char* w = (char*)d_ws;
  u16* Wt_a = (u16*)w;                w += (size_t)512 * 1024 * 2;
  u16* Wt_c = (u16*)w;                w += (size_t)512 * 1024 * 2;
  float* partJ = (float*)w;           w += (size_t)2 * 51200 * 4;
  u16*   preC = (u16*)w;              w += (size_t)25600 * 512 * 2;
  float* hWa  = (float*)w;            w += (size_t)BB * DECD * 4;
  float* scC  = (float*)w;            w += (size_t)BB * S1D * 4;
  float* wgt  = (float*)w;            w += (size_t)BB * E2D * 4;
  float* wpart = (float*)w;           w += (size_t)4 * BB * E2D * 4;
  u16*   x_bf = (u16*)w;              w += (size_t)BB * 1280 * 2;
  u16*   hid_bf = (u16*)w;            w += (size_t)BB * DECD * 2;
  float* gx   = (float*)w;            w += (size_t)BB * 1536 * 4;
  float* gh   = (float*)w;            w += (size_t)BB * 1536 * 4;
  u16*   st_bf = (u16*)w;             w += (size_t)BB * 1536 * 2;
  float* pg   = (float*)w;            w += 512;

  float* out  = (float*)d_out;
  float* hnew = out + (size_t)BB * VV;

  // fused prep
  k_prep<<<1440, 256, 0, stream>>>(attn_W, copy_W, Wt_a, Wt_c,
                                   hidden, hid_bf, attn_b, hWa,
                                   input, embedding, x_bf);

  // combined joint-attn + copy-preactivation energy GEMM (r19 raceless structure)
  gemm_energy_jc<<<dim3(2, JY + 400), 256, 0, stream>>>(
      enc1, enc2, Wt_a, Wt_c, hWa, attn_v, partJ, preC);

  // weighted context with inline joint softmax
  k_wpart_sm<<<dim3(BB, 2, 4), 256, 0, stream>>>(partJ, enc1, enc2, mask1, mask2, wpart);
  k_wsum_x<<<512, 256, 0, stream>>>(wpart, wgt, x_bf);

  // GRU (48 BN=64 blocks)
  gemm_gru2<<<48, 512, 0, stream>>>(x_bf, gru_Wih, gru_bih, gx,
                                    hid_bf, gru_Whh, gru_bhh, gh);
  k_gru_concat<<<BB, 256, 0, stream>>>(gx, gh, hidden, wgt, hnew, st_bf);

  // vocab logits + p_gen + copy-epilogue (co-resident; small blocks first)
  gemm_fc3c<<<256 + 782, 512, 0, stream>>>(
      st_bf, fc_W, fc_b, out, VV, 1536,
      wgt, input, embedding, gate_W, gate_b, pg,
      hnew, copy_W, copy_b, copy_v, preC, scC);

  // final distribution (vocab softmax + copy softmax + scatter)
  k_vocab_sc2<<<BB, 256, 0, stream>>>(out, pg, scC, mask1, triple, src1);
}